// Round 18
// baseline (316.611 us; speedup 1.0000x reference)
//
#include <hip/hip_runtime.h>

typedef __bf16 bf16x8 __attribute__((ext_vector_type(8)));
typedef float f32x4 __attribute__((ext_vector_type(4)));
typedef unsigned short u16x4 __attribute__((ext_vector_type(4)));

#define NBATCH 8
#define LPTS   16384
#define CDIM   256
#define KANC   64
#define DIN    512
#define H1DIM  128
#define H2DIM  256
#define TM     64
#define USTR   40       // u-LDS row stride (u16): 32 payload + 8 pad

__device__ __forceinline__ unsigned short f2b(float f){
  __bf16 h = (__bf16)f;                 // native v_cvt, RNE
  return __builtin_bit_cast(unsigned short, h);
}

__device__ __forceinline__ bf16x8 cvt8(float4 a, float4 b){
  bf16x8 r;
  r[0]=(__bf16)a.x; r[1]=(__bf16)a.y; r[2]=(__bf16)a.z; r[3]=(__bf16)a.w;
  r[4]=(__bf16)b.x; r[5]=(__bf16)b.y; r[6]=(__bf16)b.z; r[7]=(__bf16)b.w;
  return r;
}

// Barrier WITHOUT vmcnt drain: flush this wave's LDS ops, rendezvous, fence
// the compiler. Outstanding global loads stay in flight.
#define LBAR() do{ \
  asm volatile("s_waitcnt lgkmcnt(0)" ::: "memory"); \
  __builtin_amdgcn_s_barrier(); \
  asm volatile("" ::: "memory"); \
} while(0)

// wt[0..65536) = W1T[128][512]; wt[65536..98304) = W2T[256][128];
// wt[98304..163840) = W3T[256][256]   (all bf16)
__global__ __launch_bounds__(256) void prep_weights(
    const float* __restrict__ W1, const float* __restrict__ W2,
    const float* __restrict__ W3, unsigned short* __restrict__ wt){
  int id = blockIdx.x * 256 + threadIdx.x;
  if (id < 65536){
    int r = id >> 9, c = id & 511;
    wt[id] = f2b(W1[c * 128 + r]);
  } else if (id < 98304){
    int t = id - 65536; int r = t >> 7, c = t & 127;
    wt[id] = f2b(W2[c * 256 + r]);
  } else if (id < 163840){
    int t = id - 98304; int r = t >> 8, c = t & 255;
    wt[id] = f2b(W3[c * 256 + r]);
  }
}

// Rank-11 collapse of the S-half of GEMM1.
// coef[comb][12][128] f32 (row 11 cols 0..3 = SAx,SAy,SAz,SA2).
// cbf[comb][128][32] bf16: cc_j per column, zero-padded j=11..31.
__global__ __launch_bounds__(128) void prep_coef(
    const float* __restrict__ pts0, const float* __restrict__ pts1,
    const int* __restrict__ anc_i, const int* __restrict__ anc_j,
    const float* __restrict__ W1, float* __restrict__ coef,
    unsigned short* __restrict__ cbf){
  const int comb = blockIdx.x;          // 0..15
  const int strm = comb >> 3, n = comb & 7;
  const int col  = threadIdx.x;         // 0..127
  __shared__ float4 anc[64];
  const float* pts  = strm ? pts1 : pts0;
  const int*   anci = strm ? anc_j : anc_i;
  if (col < 64){
    int ai = anci[n * KANC + col];
    const float* ap = pts + ((size_t)n * LPTS + ai) * 3;
    anc[col] = make_float4(ap[0], ap[1], ap[2], 0.f);
  }
  __syncthreads();
  float SX=0,CX=0,SY=0,CY=0,SZ=0,CZ=0,SD=0,ADx=0,ADy=0,ADz=0,CD2=0;
  float SAx=0,SAy=0,SAz=0,SA2=0;
  for (int k = 0; k < KANC; ++k){
    float4 a = anc[k];
    float ak2 = a.x*a.x + a.y*a.y + a.z*a.z;
    float wx = W1[(256 + k) * 128 + col];
    float wy = W1[(320 + k) * 128 + col];
    float wz = W1[(384 + k) * 128 + col];
    float wd = W1[(448 + k) * 128 + col];
    SX += wx; CX += a.x * wx;
    SY += wy; CY += a.y * wy;
    SZ += wz; CZ += a.z * wz;
    SD += wd; ADx += a.x * wd; ADy += a.y * wd; ADz += a.z * wd;
    CD2 += ak2 * wd;
    SAx += a.x; SAy += a.y; SAz += a.z; SA2 += ak2;
  }
  float* cf = coef + (size_t)comb * 12 * 128;
  cf[ 0*128+col]=SX;  cf[ 1*128+col]=CX;  cf[ 2*128+col]=SY;  cf[ 3*128+col]=CY;
  cf[ 4*128+col]=SZ;  cf[ 5*128+col]=CZ;  cf[ 6*128+col]=SD;  cf[ 7*128+col]=ADx;
  cf[ 8*128+col]=ADy; cf[ 9*128+col]=ADz; cf[10*128+col]=CD2;
  if (col == 0) cf[11*128+0] = SAx;
  if (col == 1) cf[11*128+1] = SAy;
  if (col == 2) cf[11*128+2] = SAz;
  if (col == 3) cf[11*128+3] = SA2;
  unsigned short* cb = cbf + ((size_t)comb * 128 + col) * 32;
  cb[0]=f2b(SX);  cb[1]=f2b(CX);  cb[2]=f2b(SY);  cb[3]=f2b(CY);
  cb[4]=f2b(SZ);  cb[5]=f2b(CZ);  cb[6]=f2b(SD);  cb[7]=f2b(ADx);
  cb[8]=f2b(ADy); cb[9]=f2b(ADz); cb[10]=f2b(CD2);
  #pragma unroll
  for (int j = 11; j < 32; ++j) cb[j] = 0;
}

// TM=64, 512 threads. G1: 4M x 2N wave grid, A from GLOBAL regs (no feat
// LDS staging), K=288 fold (u_j 9th k-step from 5KB u-LDS). G2/G3: 1M x 8N
// from h1s/h2s LDS, R14-verbatim. LDS 53 KiB -> 2 blocks/CU. 3 LBARs.
__global__ __launch_bounds__(512, 4) void fused(
    const float* __restrict__ feat0, const float* __restrict__ feat1,
    const float* __restrict__ pts0, const float* __restrict__ pts1,
    const int* __restrict__ anc_i, const int* __restrict__ anc_j,
    const float* __restrict__ b1, const float* __restrict__ b2,
    const float* __restrict__ b3, const unsigned short* __restrict__ wt,
    const float* __restrict__ coef, const unsigned short* __restrict__ cbf,
    float* __restrict__ out)
{
  __shared__ unsigned short ulds[TM * USTR];  // 5 KiB: u_j bf16 per point
  __shared__ unsigned short h1s[TM * H1DIM];  // 16 KiB
  __shared__ unsigned short h2s[TM * H2DIM];  // 32 KiB

  const int tid  = threadIdx.x;
  const int wg   = blockIdx.x;
  const int strm = wg >> 11;
  const int n    = (wg >> 8) & 7;
  const int l0   = (wg & 255) * TM;
  const int comb = (strm << 3) | n;

  const float* feat = strm ? feat1 : feat0;
  const float* pts  = strm ? pts1 : pts0;
  const int*   anci = strm ? anc_j : anc_i;
  const float* cf   = coef + (size_t)comb * 12 * 128;

  const int lane = tid & 63;
  const int w    = tid >> 6;
  const int lr   = lane & 15;
  const int lg   = lane >> 4;
  const int wr   = w >> 1, wc = w & 1;        // G1: 4M x 2N
  const int r0   = wr * 16;
  const int col0 = w * 32;                    // G2/G3 column base
  const unsigned short* w2t = wt + 65536;
  const unsigned short* w3t = wt + 98304;
  const size_t fB = (size_t)n * LPTS;

  // ---- top-of-kernel loads ----
  float ax, ay, az;                           // own-lane anchor
  {
    int ai = anci[n * KANC + lane];
    const float* ap = pts + (fB + ai) * 3;
    ax = ap[0]; ay = ap[1]; az = ap[2];
  }
  const float* pp = pts + (fB + l0 + (tid >> 3)) * 3;
  float px = pp[0], py = pp[1], pz = pp[2];
  float SAx = cf[11*128+0], SAy = cf[11*128+1], SAz = cf[11*128+2], SA2 = cf[11*128+3];
  float bias1v[4];
  #pragma unroll
  for (int nf = 0; nf < 4; ++nf) bias1v[nf] = b1[wc * 64 + nf * 16 + lr];

  // ---- G1 A-batch: own 16 rows from global, cvt -> bf16 (32 VGPR) ----
  bf16x8 a1b[8];
  {
    const float4* fp = (const float4*)(feat + (fB + l0 + r0 + lr) * CDIM);
    #pragma unroll
    for (int kk = 0; kk < 8; ++kk){
      float4 lo = fp[kk * 8 + lg * 2];
      float4 hi = fp[kk * 8 + lg * 2 + 1];
      a1b[kk] = cvt8(lo, hi);
    }
  }

  // ---- Phase B: u_j (bf16) -> ulds[64][40] (cols 0..31; 12..31 zero) ----
  {
    const int l   = tid >> 3;             // 0..63
    const int sub = tid & 7;
    float s0 = 0.f, s1 = 0.f, s2 = 0.f;
    #pragma unroll
    for (int i = 0; i < 8; ++i){
      int src = sub * 8 + i;
      float akx = __shfl(ax, src, 64);
      float aky = __shfl(ay, src, 64);
      float akz = __shfl(az, src, 64);
      s0 += fabsf(px - akx); s1 += fabsf(py - aky); s2 += fabsf(pz - akz);
    }
    #pragma unroll
    for (int m = 1; m <= 4; m <<= 1){
      s0 += __shfl_xor(s0, m, 64);
      s1 += __shfl_xor(s1, m, 64);
      s2 += __shfl_xor(s2, m, 64);
    }
    float pp2 = px*px + py*py + pz*pz;
    float s3 = 64.f * pp2 - 2.f * (px*SAx + py*SAy + pz*SAz) + SA2;
    float i0 = 1.f/s0, i1 = 1.f/s1, i2 = 1.f/s2, i3 = 1.f/s3;
    // u0=i0*px u1=-i0 u2=i1*py u3=-i1 u4=i2*pz u5=-i2 u6=i3*pp2
    // u7=-2i3*px u8=-2i3*py u9=-2i3*pz u10=i3 u11..31=0
    float a0, a1, a2, a3;
    if (sub == 0){ a0 = i0*px;      a1 = -i0;       a2 = i1*py;  a3 = -i1; }
    else if (sub == 1){ a0 = i2*pz; a1 = -i2;       a2 = i3*pp2; a3 = -2.f*i3*px; }
    else if (sub == 2){ a0 = -2.f*i3*py; a1 = -2.f*i3*pz; a2 = i3; a3 = 0.f; }
    else { a0 = a1 = a2 = a3 = 0.f; }
    u16x4 pk = { f2b(a0), f2b(a1), f2b(a2), f2b(a3) };
    *(u16x4*)&ulds[l * USTR + sub * 4] = pk;
  }

  // ---- G1 B-batch first half (kk=0..3 x 4 nf): issued before bar1 ----
  bf16x8 b1b[16];
  #pragma unroll
  for (int kk = 0; kk < 4; ++kk){
    #pragma unroll
    for (int nf = 0; nf < 4; ++nf)
      b1b[kk * 4 + nf] =
        *(const bf16x8*)&wt[(wc * 64 + nf * 16 + lr) * DIN + kk * 32 + lg * 8];
  }

  LBAR();                                 // bar1: ulds ready

  // ---- GEMM1: A-regs [16,288] @ [W1T|cc] -> +b1 -> relu -> h1s ----
  {
    f32x4 acc[4] = {};
    #pragma unroll
    for (int kk = 0; kk < 4; ++kk){
      #pragma unroll
      for (int nf = 0; nf < 4; ++nf)
        acc[nf] = __builtin_amdgcn_mfma_f32_16x16x32_bf16(a1b[kk], b1b[kk*4+nf], acc[nf], 0, 0, 0);
    }
    bf16x8 b1c[16];
    #pragma unroll
    for (int kk = 0; kk < 4; ++kk){
      #pragma unroll
      for (int nf = 0; nf < 4; ++nf)
        b1c[kk * 4 + nf] =
          *(const bf16x8*)&wt[(wc * 64 + nf * 16 + lr) * DIN + (kk + 4) * 32 + lg * 8];
    }
    #pragma unroll
    for (int kk = 0; kk < 4; ++kk){
      #pragma unroll
      for (int nf = 0; nf < 4; ++nf)
        acc[nf] = __builtin_amdgcn_mfma_f32_16x16x32_bf16(a1b[kk+4], b1c[kk*4+nf], acc[nf], 0, 0, 0);
    }
    // 9th k-step: structured term (u_j from ulds, cc from cbf)
    bf16x8 au = *(const bf16x8*)&ulds[(r0 + lr) * USTR + lg * 8];
    #pragma unroll
    for (int nf = 0; nf < 4; ++nf){
      bf16x8 bcb = *(const bf16x8*)&cbf[((size_t)comb * 128 + wc * 64 + nf * 16 + lr) * 32 + lg * 8];
      acc[nf] = __builtin_amdgcn_mfma_f32_16x16x32_bf16(au, bcb, acc[nf], 0, 0, 0);
    }
    #pragma unroll
    for (int nf = 0; nf < 4; ++nf){
      int col = wc * 64 + nf * 16 + lr;
      #pragma unroll
      for (int r = 0; r < 4; ++r){
        int row = r0 + lg * 4 + r;
        float v = fmaxf(acc[nf][r] + bias1v[nf], 0.f);
        h1s[(row * H1DIM + col) ^ ((row & 7) << 3)] = f2b(v);
      }
    }
  }

  // ---- G2 B-batch: 8 loads, issued before bar2 ----
  bf16x8 b2b[8];
  #pragma unroll
  for (int kk = 0; kk < 4; ++kk){
    int kb = kk * 32 + lg * 8;
    b2b[kk * 2    ] = *(const bf16x8*)&w2t[(col0      + lr) * H1DIM + kb];
    b2b[kk * 2 + 1] = *(const bf16x8*)&w2t[(col0 + 16 + lr) * H1DIM + kb];
  }

  LBAR();                                 // bar2: h1s ready

  // ---- GEMM2: h1s[64,128] @ W2 -> relu -> h2s[64,256] ----
  {
    f32x4 acc[4][2] = {};
    #pragma unroll
    for (int kk = 0; kk < 4; ++kk){
      int kb = kk * 32 + lg * 8;
      #pragma unroll
      for (int m = 0; m < 4; ++m){
        int row = m * 16 + lr;
        bf16x8 a = *(const bf16x8*)&h1s[(row * H1DIM + kb) ^ ((row & 7) << 3)];
        acc[m][0] = __builtin_amdgcn_mfma_f32_16x16x32_bf16(a, b2b[kk*2  ], acc[m][0], 0, 0, 0);
        acc[m][1] = __builtin_amdgcn_mfma_f32_16x16x32_bf16(a, b2b[kk*2+1], acc[m][1], 0, 0, 0);
      }
    }
    #pragma unroll
    for (int nt = 0; nt < 2; ++nt){
      int col = col0 + nt * 16 + lr;
      float bias = b2[col];
      #pragma unroll
      for (int m = 0; m < 4; ++m){
        #pragma unroll
        for (int r = 0; r < 4; ++r){
          int row = m * 16 + lg * 4 + r;
          float v = fmaxf(acc[m][nt][r] + bias, 0.f);
          h2s[(row * H2DIM + col) ^ ((row & 7) << 3)] = f2b(v);
        }
      }
    }
  }

  // ---- G3 B-batch 1: 8 loads, issued before bar3 ----
  bf16x8 b3b[8];
  #pragma unroll
  for (int kk = 0; kk < 4; ++kk){
    int kb = kk * 32 + lg * 8;
    b3b[kk * 2    ] = *(const bf16x8*)&w3t[(col0      + lr) * H2DIM + kb];
    b3b[kk * 2 + 1] = *(const bf16x8*)&w3t[(col0 + 16 + lr) * H2DIM + kb];
  }

  LBAR();                                 // bar3: h2s ready

  // ---- GEMM3: h2s[64,256] @ W3 -> + b3 -> out (f32) ----
  {
    f32x4 acc[4][2] = {};
    #pragma unroll
    for (int kk = 0; kk < 4; ++kk){
      int kb = kk * 32 + lg * 8;
      #pragma unroll
      for (int m = 0; m < 4; ++m){
        int row = m * 16 + lr;
        bf16x8 a = *(const bf16x8*)&h2s[(row * H2DIM + kb) ^ ((row & 7) << 3)];
        acc[m][0] = __builtin_amdgcn_mfma_f32_16x16x32_bf16(a, b3b[kk*2  ], acc[m][0], 0, 0, 0);
        acc[m][1] = __builtin_amdgcn_mfma_f32_16x16x32_bf16(a, b3b[kk*2+1], acc[m][1], 0, 0, 0);
      }
    }
    #pragma unroll
    for (int kk = 0; kk < 4; ++kk){
      int kb = (kk + 4) * 32 + lg * 8;
      b3b[kk * 2    ] = *(const bf16x8*)&w3t[(col0      + lr) * H2DIM + kb];
      b3b[kk * 2 + 1] = *(const bf16x8*)&w3t[(col0 + 16 + lr) * H2DIM + kb];
    }
    #pragma unroll
    for (int kk = 0; kk < 4; ++kk){
      int kb = (kk + 4) * 32 + lg * 8;
      #pragma unroll
      for (int m = 0; m < 4; ++m){
        int row = m * 16 + lr;
        bf16x8 a = *(const bf16x8*)&h2s[(row * H2DIM + kb) ^ ((row & 7) << 3)];
        acc[m][0] = __builtin_amdgcn_mfma_f32_16x16x32_bf16(a, b3b[kk*2  ], acc[m][0], 0, 0, 0);
        acc[m][1] = __builtin_amdgcn_mfma_f32_16x16x32_bf16(a, b3b[kk*2+1], acc[m][1], 0, 0, 0);
      }
    }
    float* ob = out + (((size_t)strm * NBATCH + n) * LPTS + l0) * CDIM;
    #pragma unroll
    for (int nt = 0; nt < 2; ++nt){
      int col = col0 + nt * 16 + lr;
      float bias = b3[col];
      #pragma unroll
      for (int m = 0; m < 4; ++m){
        #pragma unroll
        for (int r = 0; r < 4; ++r){
          int row = m * 16 + lg * 4 + r;
          ob[(size_t)row * CDIM + col] = acc[m][nt][r] + bias;
        }
      }
    }
  }
}

extern "C" void kernel_launch(void* const* d_in, const int* in_sizes, int n_in,
                              void* d_out, int out_size, void* d_ws, size_t ws_size,
                              hipStream_t stream){
  const float* feat0 = (const float*)d_in[0];
  const float* feat1 = (const float*)d_in[1];
  const float* pts0  = (const float*)d_in[2];
  const float* pts1  = (const float*)d_in[3];
  const int*   anci  = (const int*)d_in[4];
  const int*   ancj  = (const int*)d_in[5];
  const float* W1    = (const float*)d_in[6];
  const float* b1    = (const float*)d_in[7];
  const float* W2    = (const float*)d_in[8];
  const float* b2    = (const float*)d_in[9];
  const float* W3    = (const float*)d_in[10];
  const float* b3    = (const float*)d_in[11];
  unsigned short* wt = (unsigned short*)d_ws;
  float* coef = (float*)((char*)d_ws + 327680);
  unsigned short* cbf = (unsigned short*)((char*)d_ws + 327680 + 98304);
  float* out = (float*)d_out;

  prep_weights<<<640, 256, 0, stream>>>(W1, W2, W3, wt);
  prep_coef<<<16, 128, 0, stream>>>(pts0, pts1, anci, ancj, W1, coef, cbf);
  fused<<<4096, 512, 0, stream>>>(feat0, feat1, pts0, pts1, anci, ancj,
                                  b1, b2, b3, wt, coef, cbf, out);
}

// Round 19
// 221.039 us; speedup vs baseline: 1.4324x; 1.4324x over previous
//
#include <hip/hip_runtime.h>

typedef __bf16 bf16x8 __attribute__((ext_vector_type(8)));
typedef float f32x4 __attribute__((ext_vector_type(4)));
typedef unsigned short u16x4 __attribute__((ext_vector_type(4)));
typedef unsigned short u16x8 __attribute__((ext_vector_type(8)));

#define NBATCH 8
#define LPTS   16384
#define CDIM   256
#define KANC   64
#define DIN    512
#define H1DIM  128
#define H2DIM  256
#define TM     64

__device__ __forceinline__ unsigned short f2b(float f){
  __bf16 h = (__bf16)f;                 // native v_cvt, RNE
  return __builtin_bit_cast(unsigned short, h);
}

// Barrier WITHOUT vmcnt drain.
#define LBAR() do{ \
  asm volatile("s_waitcnt lgkmcnt(0)" ::: "memory"); \
  __builtin_amdgcn_s_barrier(); \
  asm volatile("" ::: "memory"); \
} while(0)

// wt[0..65536) = W1T[128][512]; wt[65536..98304) = W2T[256][128];
// wt[98304..163840) = W3T[256][256]   (all bf16)
__global__ __launch_bounds__(256) void prep_weights(
    const float* __restrict__ W1, const float* __restrict__ W2,
    const float* __restrict__ W3, unsigned short* __restrict__ wt){
  int id = blockIdx.x * 256 + threadIdx.x;
  if (id < 65536){
    int r = id >> 9, c = id & 511;
    wt[id] = f2b(W1[c * 128 + r]);
  } else if (id < 98304){
    int t = id - 65536; int r = t >> 7, c = t & 127;
    wt[id] = f2b(W2[c * 256 + r]);
  } else if (id < 163840){
    int t = id - 98304; int r = t >> 8, c = t & 255;
    wt[id] = f2b(W3[c * 256 + r]);
  }
}

// Rank-11 collapse of the S-half of GEMM1. coef[comb][12][128] f32.
__global__ __launch_bounds__(128) void prep_coef(
    const float* __restrict__ pts0, const float* __restrict__ pts1,
    const int* __restrict__ anc_i, const int* __restrict__ anc_j,
    const float* __restrict__ W1, float* __restrict__ coef){
  const int comb = blockIdx.x;          // 0..15
  const int strm = comb >> 3, n = comb & 7;
  const int col  = threadIdx.x;         // 0..127
  __shared__ float4 anc[64];
  const float* pts  = strm ? pts1 : pts0;
  const int*   anci = strm ? anc_j : anc_i;
  if (col < 64){
    int ai = anci[n * KANC + col];
    const float* ap = pts + ((size_t)n * LPTS + ai) * 3;
    anc[col] = make_float4(ap[0], ap[1], ap[2], 0.f);
  }
  __syncthreads();
  float SX=0,CX=0,SY=0,CY=0,SZ=0,CZ=0,SD=0,ADx=0,ADy=0,ADz=0,CD2=0;
  float SAx=0,SAy=0,SAz=0,SA2=0;
  for (int k = 0; k < KANC; ++k){
    float4 a = anc[k];
    float ak2 = a.x*a.x + a.y*a.y + a.z*a.z;
    float wx = W1[(256 + k) * 128 + col];
    float wy = W1[(320 + k) * 128 + col];
    float wz = W1[(384 + k) * 128 + col];
    float wd = W1[(448 + k) * 128 + col];
    SX += wx; CX += a.x * wx;
    SY += wy; CY += a.y * wy;
    SZ += wz; CZ += a.z * wz;
    SD += wd; ADx += a.x * wd; ADy += a.y * wd; ADz += a.z * wd;
    CD2 += ak2 * wd;
    SAx += a.x; SAy += a.y; SAz += a.z; SA2 += ak2;
  }
  float* cf = coef + (size_t)comb * 12 * 128;
  cf[ 0*128+col]=SX;  cf[ 1*128+col]=CX;  cf[ 2*128+col]=SY;  cf[ 3*128+col]=CY;
  cf[ 4*128+col]=SZ;  cf[ 5*128+col]=CZ;  cf[ 6*128+col]=SD;  cf[ 7*128+col]=ADx;
  cf[ 8*128+col]=ADy; cf[ 9*128+col]=ADz; cf[10*128+col]=CD2;
  if (col == 0) cf[11*128+0] = SAx;
  if (col == 1) cf[11*128+1] = SAy;
  if (col == 2) cf[11*128+2] = SAz;
  if (col == 3) cf[11*128+3] = SA2;
}

// K1: Phase A + Phase B + GEMM1 -> h1g[comb][16384][128] bf16.
// R14-verbatim bodies; extra barrier + coalesced LDS->HBM h1 copy-out.
__global__ __launch_bounds__(512, 4) void k1(
    const float* __restrict__ feat0, const float* __restrict__ feat1,
    const float* __restrict__ pts0, const float* __restrict__ pts1,
    const int* __restrict__ anc_i, const int* __restrict__ anc_j,
    const float* __restrict__ b1, const unsigned short* __restrict__ wt,
    const float* __restrict__ coef, unsigned short* __restrict__ h1g)
{
  __shared__ unsigned short xs[TM * 256];     // 32 KiB
  __shared__ unsigned short h1s[TM * H1DIM];  // 16 KiB
  __shared__ float scal[TM][12];              // 3 KiB

  const int tid  = threadIdx.x;
  const int wg   = blockIdx.x;
  const int strm = wg >> 11;
  const int n    = (wg >> 8) & 7;
  const int l0   = (wg & 255) * TM;
  const int comb = (strm << 3) | n;

  const float* feat = strm ? feat1 : feat0;
  const float* pts  = strm ? pts1 : pts0;
  const int*   anci = strm ? anc_j : anc_i;
  const float* cf   = coef + (size_t)comb * 12 * 128;

  const int lane = tid & 63;
  const int w    = tid >> 6;
  const int lr   = lane & 15;
  const int lg   = lane >> 4;
  const int col1 = w * 16 + lr;
  const unsigned short* wrow1 = wt + col1 * DIN;

  float ax, ay, az;
  {
    int ai = anci[n * KANC + lane];
    const float* ap = pts + ((size_t)n * LPTS + ai) * 3;
    ax = ap[0]; ay = ap[1]; az = ap[2];
  }
  const float* pp = pts + ((size_t)n * LPTS + l0 + (tid >> 3)) * 3;
  float px = pp[0], py = pp[1], pz = pp[2];
  float SAx = cf[11*128+0], SAy = cf[11*128+1], SAz = cf[11*128+2], SA2 = cf[11*128+3];
  float cc[11];
  #pragma unroll
  for (int j = 0; j < 11; ++j) cc[j] = cf[j * 128 + col1];
  float bias1 = b1[col1];

  // ---- Phase A ----
  {
    const float4* fb = (const float4*)(feat + ((size_t)n * LPTS + l0) * CDIM);
    #pragma unroll
    for (int it = 0; it < 8; ++it){
      int flat = it * 512 + tid;
      int r = flat >> 6, c4 = flat & 63;
      float4 v = fb[flat];
      int e = (r * 256 + c4 * 4) ^ ((r & 7) << 3);
      u16x4 pk = { f2b(v.x), f2b(v.y), f2b(v.z), f2b(v.w) };
      *(u16x4*)&xs[e] = pk;
    }
  }

  // ---- Phase B ----
  {
    const int l   = tid >> 3;
    const int sub = tid & 7;
    float s0 = 0.f, s1 = 0.f, s2 = 0.f;
    #pragma unroll
    for (int i = 0; i < 8; ++i){
      int src = sub * 8 + i;
      float akx = __shfl(ax, src, 64);
      float aky = __shfl(ay, src, 64);
      float akz = __shfl(az, src, 64);
      s0 += fabsf(px - akx); s1 += fabsf(py - aky); s2 += fabsf(pz - akz);
    }
    #pragma unroll
    for (int m = 1; m <= 4; m <<= 1){
      s0 += __shfl_xor(s0, m, 64);
      s1 += __shfl_xor(s1, m, 64);
      s2 += __shfl_xor(s2, m, 64);
    }
    float pp2 = px*px + py*py + pz*pz;
    float s3 = 64.f * pp2 - 2.f * (px*SAx + py*SAy + pz*SAz) + SA2;
    float i0 = 1.f/s0, i1 = 1.f/s1, i2 = 1.f/s2, i3 = 1.f/s3;
    float u;
    switch (sub){
      case 0: u = i0 * px;       break;
      case 1: u = -i0;           break;
      case 2: u = i1 * py;       break;
      case 3: u = -i1;           break;
      case 4: u = i2 * pz;       break;
      case 5: u = -i2;           break;
      case 6: u = i3 * pp2;      break;
      default: u = -2.f*i3*px;   break;
    }
    scal[l][sub] = u;
    if (sub < 3){
      float u2 = (sub == 0) ? -2.f*i3*py : (sub == 1) ? -2.f*i3*pz : i3;
      scal[l][8 + sub] = u2;
    }
  }

  // ---- G1 B-batch before bar ----
  bf16x8 b1b[8];
  #pragma unroll
  for (int kk = 0; kk < 8; ++kk)
    b1b[kk] = *(const bf16x8*)&wrow1[kk * 32 + lg * 8];

  LBAR();

  // ---- GEMM1 + rank-11 epilogue -> h1s ----
  {
    f32x4 acc[4] = {};
    #pragma unroll
    for (int kk = 0; kk < 8; ++kk){
      int kb = kk * 32 + lg * 8;
      #pragma unroll
      for (int m = 0; m < 4; ++m){
        int row = m * 16 + lr;
        bf16x8 a = *(const bf16x8*)&xs[(row * 256 + kb) ^ ((row & 7) << 3)];
        acc[m] = __builtin_amdgcn_mfma_f32_16x16x32_bf16(a, b1b[kk], acc[m], 0, 0, 0);
      }
    }
    #pragma unroll
    for (int m = 0; m < 4; ++m){
      #pragma unroll
      for (int r = 0; r < 4; ++r){
        int row = m * 16 + lg * 4 + r;
        f32x4 ua = *(const f32x4*)&scal[row][0];
        f32x4 ub = *(const f32x4*)&scal[row][4];
        f32x4 uc = *(const f32x4*)&scal[row][8];
        float s = acc[m][r] + bias1;
        s += ua[0]*cc[0] + ua[1]*cc[1] + ua[2]*cc[2] + ua[3]*cc[3];
        s += ub[0]*cc[4] + ub[1]*cc[5] + ub[2]*cc[6] + ub[3]*cc[7];
        s += uc[0]*cc[8] + uc[1]*cc[9] + uc[2]*cc[10];
        float v = fmaxf(s, 0.f);
        h1s[(row * H1DIM + col1) ^ ((row & 7) << 3)] = f2b(v);
      }
    }
  }

  LBAR();

  // ---- h1s -> h1g (coalesced 16B/lane) ----
  {
    unsigned short* hg = h1g + ((size_t)comb * LPTS + l0) * H1DIM;
    #pragma unroll
    for (int it = 0; it < 2; ++it){
      int flat = it * 512 + tid;           // 1024 chunks of 8 u16
      int row = flat >> 4, c8 = flat & 15;
      int off = row * H1DIM + c8 * 8;
      u16x8 v = *(const u16x8*)&h1s[off ^ ((row & 7) << 3)];
      *(u16x8*)&hg[off] = v;
    }
  }
}

// K23: h1g tile -> LDS -> GEMM2 -> h2s -> GEMM3 -> out. Chain: 2 barriers.
__global__ __launch_bounds__(512, 4) void k23(
    const unsigned short* __restrict__ h1g,
    const float* __restrict__ b2, const float* __restrict__ b3,
    const unsigned short* __restrict__ wt, float* __restrict__ out)
{
  __shared__ unsigned short h1s[TM * H1DIM];  // 16 KiB
  __shared__ unsigned short h2s[TM * H2DIM];  // 32 KiB

  const int tid  = threadIdx.x;
  const int wg   = blockIdx.x;
  const int strm = wg >> 11;
  const int n    = (wg >> 8) & 7;
  const int l0   = (wg & 255) * TM;
  const int comb = (strm << 3) | n;

  const int lane = tid & 63;
  const int w    = tid >> 6;
  const int lr   = lane & 15;
  const int lg   = lane >> 4;
  const int col0 = w * 32;
  const unsigned short* w2t = wt + 65536;
  const unsigned short* w3t = wt + 98304;

  float bias2a = b2[col0 + lr], bias2b = b2[col0 + 16 + lr];
  float bias3a = b3[col0 + lr], bias3b = b3[col0 + 16 + lr];

  // ---- load h1 tile (coalesced) -> h1s (swizzled) ----
  {
    const unsigned short* hg = h1g + ((size_t)comb * LPTS + l0) * H1DIM;
    #pragma unroll
    for (int it = 0; it < 2; ++it){
      int flat = it * 512 + tid;
      int row = flat >> 4, c8 = flat & 15;
      int off = row * H1DIM + c8 * 8;
      u16x8 v = *(const u16x8*)&hg[off];
      *(u16x8*)&h1s[off ^ ((row & 7) << 3)] = v;
    }
  }

  // ---- G2 B-batch before bar1 ----
  bf16x8 b2b[8];
  #pragma unroll
  for (int kk = 0; kk < 4; ++kk){
    int kb = kk * 32 + lg * 8;
    b2b[kk * 2    ] = *(const bf16x8*)&w2t[(col0      + lr) * H1DIM + kb];
    b2b[kk * 2 + 1] = *(const bf16x8*)&w2t[(col0 + 16 + lr) * H1DIM + kb];
  }

  LBAR();                                 // h1s ready

  // ---- GEMM2 -> h2s ----
  {
    f32x4 acc[4][2] = {};
    #pragma unroll
    for (int kk = 0; kk < 4; ++kk){
      int kb = kk * 32 + lg * 8;
      #pragma unroll
      for (int m = 0; m < 4; ++m){
        int row = m * 16 + lr;
        bf16x8 a = *(const bf16x8*)&h1s[(row * H1DIM + kb) ^ ((row & 7) << 3)];
        acc[m][0] = __builtin_amdgcn_mfma_f32_16x16x32_bf16(a, b2b[kk*2  ], acc[m][0], 0, 0, 0);
        acc[m][1] = __builtin_amdgcn_mfma_f32_16x16x32_bf16(a, b2b[kk*2+1], acc[m][1], 0, 0, 0);
      }
    }
    #pragma unroll
    for (int nt = 0; nt < 2; ++nt){
      float bias = nt ? bias2b : bias2a;
      int col = col0 + nt * 16 + lr;
      #pragma unroll
      for (int m = 0; m < 4; ++m){
        #pragma unroll
        for (int r = 0; r < 4; ++r){
          int row = m * 16 + lg * 4 + r;
          float v = fmaxf(acc[m][nt][r] + bias, 0.f);
          h2s[(row * H2DIM + col) ^ ((row & 7) << 3)] = f2b(v);
        }
      }
    }
  }

  // ---- G3 B-batch 1 before bar2 ----
  bf16x8 b3b[8];
  #pragma unroll
  for (int kk = 0; kk < 4; ++kk){
    int kb = kk * 32 + lg * 8;
    b3b[kk * 2    ] = *(const bf16x8*)&w3t[(col0      + lr) * H2DIM + kb];
    b3b[kk * 2 + 1] = *(const bf16x8*)&w3t[(col0 + 16 + lr) * H2DIM + kb];
  }

  LBAR();                                 // h2s ready

  // ---- GEMM3 -> out ----
  {
    f32x4 acc[4][2] = {};
    #pragma unroll
    for (int kk = 0; kk < 4; ++kk){
      int kb = kk * 32 + lg * 8;
      #pragma unroll
      for (int m = 0; m < 4; ++m){
        int row = m * 16 + lr;
        bf16x8 a = *(const bf16x8*)&h2s[(row * H2DIM + kb) ^ ((row & 7) << 3)];
        acc[m][0] = __builtin_amdgcn_mfma_f32_16x16x32_bf16(a, b3b[kk*2  ], acc[m][0], 0, 0, 0);
        acc[m][1] = __builtin_amdgcn_mfma_f32_16x16x32_bf16(a, b3b[kk*2+1], acc[m][1], 0, 0, 0);
      }
    }
    #pragma unroll
    for (int kk = 0; kk < 4; ++kk){
      int kb = (kk + 4) * 32 + lg * 8;
      b3b[kk * 2    ] = *(const bf16x8*)&w3t[(col0      + lr) * H2DIM + kb];
      b3b[kk * 2 + 1] = *(const bf16x8*)&w3t[(col0 + 16 + lr) * H2DIM + kb];
    }
    #pragma unroll
    for (int kk = 0; kk < 4; ++kk){
      int kb = (kk + 4) * 32 + lg * 8;
      #pragma unroll
      for (int m = 0; m < 4; ++m){
        int row = m * 16 + lr;
        bf16x8 a = *(const bf16x8*)&h2s[(row * H2DIM + kb) ^ ((row & 7) << 3)];
        acc[m][0] = __builtin_amdgcn_mfma_f32_16x16x32_bf16(a, b3b[kk*2  ], acc[m][0], 0, 0, 0);
        acc[m][1] = __builtin_amdgcn_mfma_f32_16x16x32_bf16(a, b3b[kk*2+1], acc[m][1], 0, 0, 0);
      }
    }
    float* ob = out + (((size_t)strm * NBATCH + n) * LPTS + l0) * CDIM;
    #pragma unroll
    for (int nt = 0; nt < 2; ++nt){
      float bias = nt ? bias3b : bias3a;
      int col = col0 + nt * 16 + lr;
      #pragma unroll
      for (int m = 0; m < 4; ++m){
        #pragma unroll
        for (int r = 0; r < 4; ++r){
          int row = m * 16 + lg * 4 + r;
          ob[(size_t)row * CDIM + col] = acc[m][nt][r] + bias;
        }
      }
    }
  }
}

extern "C" void kernel_launch(void* const* d_in, const int* in_sizes, int n_in,
                              void* d_out, int out_size, void* d_ws, size_t ws_size,
                              hipStream_t stream){
  const float* feat0 = (const float*)d_in[0];
  const float* feat1 = (const float*)d_in[1];
  const float* pts0  = (const float*)d_in[2];
  const float* pts1  = (const float*)d_in[3];
  const int*   anci  = (const int*)d_in[4];
  const int*   ancj  = (const int*)d_in[5];
  const float* W1    = (const float*)d_in[6];
  const float* b1    = (const float*)d_in[7];
  const float* W2    = (const float*)d_in[8];
  const float* b2    = (const float*)d_in[9];
  const float* W3    = (const float*)d_in[10];
  const float* b3    = (const float*)d_in[11];
  unsigned short* wt = (unsigned short*)d_ws;
  float* coef = (float*)((char*)d_ws + 327680);
  unsigned short* h1g = (unsigned short*)((char*)d_ws + 327680 + 98304);
  float* out = (float*)d_out;

  prep_weights<<<640, 256, 0, stream>>>(W1, W2, W3, wt);
  prep_coef<<<16, 128, 0, stream>>>(pts0, pts1, anci, ancj, W1, coef);
  k1<<<4096, 512, 0, stream>>>(feat0, feat1, pts0, pts1, anci, ancj,
                               b1, wt, coef, h1g);
  k23<<<4096, 512, 0, stream>>>(h1g, b2, b3, wt, out);
}

// Round 21
// 207.098 us; speedup vs baseline: 1.5288x; 1.0673x over previous
//
#include <hip/hip_runtime.h>

typedef __bf16 bf16x8 __attribute__((ext_vector_type(8)));
typedef float f32x4 __attribute__((ext_vector_type(4)));
typedef unsigned short u16x4 __attribute__((ext_vector_type(4)));

#define NBATCH 8
#define LPTS   16384
#define CDIM   256
#define KANC   64
#define DIN    512
#define H1DIM  128
#define H2DIM  256
#define TM     64

__device__ __forceinline__ unsigned short f2b(float f){
  __bf16 h = (__bf16)f;                 // native v_cvt, RNE
  return __builtin_bit_cast(unsigned short, h);
}

// Barrier WITHOUT vmcnt drain: flush this wave's LDS ops, rendezvous, fence
// the compiler. Outstanding global loads stay in flight.
#define LBAR() do{ \
  asm volatile("s_waitcnt lgkmcnt(0)" ::: "memory"); \
  __builtin_amdgcn_s_barrier(); \
  asm volatile("" ::: "memory"); \
} while(0)

// wt[0..65536) = W1T[128][512]; wt[65536..98304) = W2T[256][128];
// wt[98304..163840) = W3T[256][256]   (all bf16)
__global__ __launch_bounds__(256) void prep_weights(
    const float* __restrict__ W1, const float* __restrict__ W2,
    const float* __restrict__ W3, unsigned short* __restrict__ wt){
  int id = blockIdx.x * 256 + threadIdx.x;
  if (id < 65536){
    int r = id >> 9, c = id & 511;
    wt[id] = f2b(W1[c * 128 + r]);
  } else if (id < 98304){
    int t = id - 65536; int r = t >> 7, c = t & 127;
    wt[id] = f2b(W2[c * 256 + r]);
  } else if (id < 163840){
    int t = id - 98304; int r = t >> 8, c = t & 255;
    wt[id] = f2b(W3[c * 256 + r]);
  }
}

// Rank-11 collapse of the S-half of GEMM1. coef[comb][12][128] f32.
__global__ __launch_bounds__(128) void prep_coef(
    const float* __restrict__ pts0, const float* __restrict__ pts1,
    const int* __restrict__ anc_i, const int* __restrict__ anc_j,
    const float* __restrict__ W1, float* __restrict__ coef){
  const int comb = blockIdx.x;          // 0..15
  const int strm = comb >> 3, n = comb & 7;
  const int col  = threadIdx.x;         // 0..127
  __shared__ float4 anc[64];
  const float* pts  = strm ? pts1 : pts0;
  const int*   anci = strm ? anc_j : anc_i;
  if (col < 64){
    int ai = anci[n * KANC + col];
    const float* ap = pts + ((size_t)n * LPTS + ai) * 3;
    anc[col] = make_float4(ap[0], ap[1], ap[2], 0.f);
  }
  __syncthreads();
  float SX=0,CX=0,SY=0,CY=0,SZ=0,CZ=0,SD=0,ADx=0,ADy=0,ADz=0,CD2=0;
  float SAx=0,SAy=0,SAz=0,SA2=0;
  for (int k = 0; k < KANC; ++k){
    float4 a = anc[k];
    float ak2 = a.x*a.x + a.y*a.y + a.z*a.z;
    float wx = W1[(256 + k) * 128 + col];
    float wy = W1[(320 + k) * 128 + col];
    float wz = W1[(384 + k) * 128 + col];
    float wd = W1[(448 + k) * 128 + col];
    SX += wx; CX += a.x * wx;
    SY += wy; CY += a.y * wy;
    SZ += wz; CZ += a.z * wz;
    SD += wd; ADx += a.x * wd; ADy += a.y * wd; ADz += a.z * wd;
    CD2 += ak2 * wd;
    SAx += a.x; SAy += a.y; SAz += a.z; SA2 += ak2;
  }
  float* cf = coef + (size_t)comb * 12 * 128;
  cf[ 0*128+col]=SX;  cf[ 1*128+col]=CX;  cf[ 2*128+col]=SY;  cf[ 3*128+col]=CY;
  cf[ 4*128+col]=SZ;  cf[ 5*128+col]=CZ;  cf[ 6*128+col]=SD;  cf[ 7*128+col]=ADx;
  cf[ 8*128+col]=ADy; cf[ 9*128+col]=ADz; cf[10*128+col]=CD2;
  if (col == 0) cf[11*128+0] = SAx;
  if (col == 1) cf[11*128+1] = SAy;
  if (col == 2) cf[11*128+2] = SAz;
  if (col == 3) cf[11*128+3] = SA2;
}

// TM=64, 512 threads (8 waves, GEMMs 1M x 8N). LDS 51 KiB. 3 LBAR barriers.
// R14 structure + NONTEMPORAL feat loads / out stores (streaming data
// bypasses L2 so the 320KB weight table stays L2-resident for B-loads).
__global__ __launch_bounds__(512, 4) void fused(
    const float* __restrict__ feat0, const float* __restrict__ feat1,
    const float* __restrict__ pts0, const float* __restrict__ pts1,
    const int* __restrict__ anc_i, const int* __restrict__ anc_j,
    const float* __restrict__ b1, const float* __restrict__ b2,
    const float* __restrict__ b3, const unsigned short* __restrict__ wt,
    const float* __restrict__ coef, float* __restrict__ out)
{
  __shared__ unsigned short xs[TM * 256];     // 32 KiB: feat tile [64][256]
  __shared__ unsigned short h1s[TM * H1DIM];  // 16 KiB
  __shared__ float scal[TM][12];              // 3 KiB: per-point u_j
  unsigned short* h2s = xs;                   // aliases xs (feat dead post-G1)

  const int tid  = threadIdx.x;
  const int wg   = blockIdx.x;
  const int strm = wg >> 11;
  const int n    = (wg >> 8) & 7;
  const int l0   = (wg & 255) * TM;

  const float* feat = strm ? feat1 : feat0;
  const float* pts  = strm ? pts1 : pts0;
  const int*   anci = strm ? anc_j : anc_i;
  const float* cf   = coef + (size_t)((strm << 3) | n) * 12 * 128;

  const int lane = tid & 63;
  const int w    = tid >> 6;
  const int lr   = lane & 15;
  const int lg   = lane >> 4;
  const int col1 = w * 16 + lr;               // G1 column
  const int col0 = w * 32;                    // G2/G3 column base
  const unsigned short* wrow1 = wt + col1 * DIN;
  const unsigned short* w2t = wt + 65536;
  const unsigned short* w3t = wt + 98304;

  // ---- top-of-kernel scalar/point loads ----
  float ax, ay, az;                           // own-lane anchor
  {
    int ai = anci[n * KANC + lane];
    const float* ap = pts + ((size_t)n * LPTS + ai) * 3;
    ax = ap[0]; ay = ap[1]; az = ap[2];
  }
  const float* pp = pts + ((size_t)n * LPTS + l0 + (tid >> 3)) * 3;
  float px = pp[0], py = pp[1], pz = pp[2];
  float SAx = cf[11*128+0], SAy = cf[11*128+1], SAz = cf[11*128+2], SA2 = cf[11*128+3];
  float cc[11];
  #pragma unroll
  for (int j = 0; j < 11; ++j) cc[j] = cf[j * 128 + col1];
  float bias1 = b1[col1];

  // ---- Phase A: feat tile -> xs[64][256] bf16 (coalesced, swizzled,
  //      NONTEMPORAL loads via ext-vector f32x4: read-once stream) ----
  {
    const f32x4* fb = (const f32x4*)(feat + ((size_t)n * LPTS + l0) * CDIM);
    #pragma unroll
    for (int it = 0; it < 8; ++it){
      int flat = it * 512 + tid;          // 4096 float4, 16B/lane coalesced
      int r = flat >> 6, c4 = flat & 63;
      f32x4 v = __builtin_nontemporal_load(&fb[flat]);
      int e = (r * 256 + c4 * 4) ^ ((r & 7) << 3);
      u16x4 pk = { f2b(v[0]), f2b(v[1]), f2b(v[2]), f2b(v[3]) };
      *(u16x4*)&xs[e] = pk;
    }
  }

  // ---- Phase B: L1 denominators via shfl + per-point scalars -> scal ----
  {
    const int l   = tid >> 3;             // 0..63
    const int sub = tid & 7;
    float s0 = 0.f, s1 = 0.f, s2 = 0.f;
    #pragma unroll
    for (int i = 0; i < 8; ++i){
      int src = sub * 8 + i;
      float akx = __shfl(ax, src, 64);
      float aky = __shfl(ay, src, 64);
      float akz = __shfl(az, src, 64);
      s0 += fabsf(px - akx); s1 += fabsf(py - aky); s2 += fabsf(pz - akz);
    }
    #pragma unroll
    for (int m = 1; m <= 4; m <<= 1){
      s0 += __shfl_xor(s0, m, 64);
      s1 += __shfl_xor(s1, m, 64);
      s2 += __shfl_xor(s2, m, 64);
    }
    float pp2 = px*px + py*py + pz*pz;
    float s3 = 64.f * pp2 - 2.f * (px*SAx + py*SAy + pz*SAz) + SA2;
    float i0 = 1.f/s0, i1 = 1.f/s1, i2 = 1.f/s2, i3 = 1.f/s3;
    float u;
    switch (sub){
      case 0: u = i0 * px;       break;
      case 1: u = -i0;           break;
      case 2: u = i1 * py;       break;
      case 3: u = -i1;           break;
      case 4: u = i2 * pz;       break;
      case 5: u = -i2;           break;
      case 6: u = i3 * pp2;      break;
      default: u = -2.f*i3*px;   break;
    }
    scal[l][sub] = u;
    if (sub < 3){
      float u2 = (sub == 0) ? -2.f*i3*py : (sub == 1) ? -2.f*i3*pz : i3;
      scal[l][8 + sub] = u2;
    }
  }

  // ---- G1 B-batch: 8 independent L2 loads, issued before bar1 ----
  bf16x8 b1b[8];
  #pragma unroll
  for (int kk = 0; kk < 8; ++kk)
    b1b[kk] = *(const bf16x8*)&wrow1[kk * 32 + lg * 8];

  LBAR();                                 // bar1: xs + scal ready

  // ---- GEMM1: feat MFMA (K=256) + rank-11 S-part -> relu -> h1s ----
  {
    f32x4 acc[4] = {};
    #pragma unroll
    for (int kk = 0; kk < 8; ++kk){
      int kb = kk * 32 + lg * 8;
      #pragma unroll
      for (int m = 0; m < 4; ++m){
        int row = m * 16 + lr;
        bf16x8 a = *(const bf16x8*)&xs[(row * 256 + kb) ^ ((row & 7) << 3)];
        acc[m] = __builtin_amdgcn_mfma_f32_16x16x32_bf16(a, b1b[kk], acc[m], 0, 0, 0);
      }
    }
    #pragma unroll
    for (int m = 0; m < 4; ++m){
      #pragma unroll
      for (int r = 0; r < 4; ++r){
        int row = m * 16 + lg * 4 + r;
        f32x4 ua = *(const f32x4*)&scal[row][0];
        f32x4 ub = *(const f32x4*)&scal[row][4];
        f32x4 uc = *(const f32x4*)&scal[row][8];
        float s = acc[m][r] + bias1;
        s += ua[0]*cc[0] + ua[1]*cc[1] + ua[2]*cc[2] + ua[3]*cc[3];
        s += ub[0]*cc[4] + ub[1]*cc[5] + ub[2]*cc[6] + ub[3]*cc[7];
        s += uc[0]*cc[8] + uc[1]*cc[9] + uc[2]*cc[10];
        float v = fmaxf(s, 0.f);
        h1s[(row * H1DIM + col1) ^ ((row & 7) << 3)] = f2b(v);
      }
    }
  }

  // ---- G2 B-batch: 8 loads (4 kk x 2 cols), issued before bar2 ----
  bf16x8 b2b[8];
  #pragma unroll
  for (int kk = 0; kk < 4; ++kk){
    int kb = kk * 32 + lg * 8;
    b2b[kk * 2    ] = *(const bf16x8*)&w2t[(col0      + lr) * H1DIM + kb];
    b2b[kk * 2 + 1] = *(const bf16x8*)&w2t[(col0 + 16 + lr) * H1DIM + kb];
  }

  LBAR();                                 // bar2: h1s ready, xs reads retired

  // ---- GEMM2: h1s[64,128] @ W2 -> relu -> h2s[64,256] (aliases xs) ----
  {
    f32x4 acc[4][2] = {};
    #pragma unroll
    for (int kk = 0; kk < 4; ++kk){
      int kb = kk * 32 + lg * 8;
      #pragma unroll
      for (int m = 0; m < 4; ++m){
        int row = m * 16 + lr;
        bf16x8 a = *(const bf16x8*)&h1s[(row * H1DIM + kb) ^ ((row & 7) << 3)];
        acc[m][0] = __builtin_amdgcn_mfma_f32_16x16x32_bf16(a, b2b[kk*2  ], acc[m][0], 0, 0, 0);
        acc[m][1] = __builtin_amdgcn_mfma_f32_16x16x32_bf16(a, b2b[kk*2+1], acc[m][1], 0, 0, 0);
      }
    }
    #pragma unroll
    for (int nt = 0; nt < 2; ++nt){
      int col = col0 + nt * 16 + lr;
      float bias = b2[col];
      #pragma unroll
      for (int m = 0; m < 4; ++m){
        #pragma unroll
        for (int r = 0; r < 4; ++r){
          int row = m * 16 + lg * 4 + r;
          float v = fmaxf(acc[m][nt][r] + bias, 0.f);
          h2s[(row * H2DIM + col) ^ ((row & 7) << 3)] = f2b(v);
        }
      }
    }
  }

  // ---- G3 B-batch 1: 8 loads (kk=0..3 x 2 cols), issued before bar3 ----
  bf16x8 b3b[8];
  #pragma unroll
  for (int kk = 0; kk < 4; ++kk){
    int kb = kk * 32 + lg * 8;
    b3b[kk * 2    ] = *(const bf16x8*)&w3t[(col0      + lr) * H2DIM + kb];
    b3b[kk * 2 + 1] = *(const bf16x8*)&w3t[(col0 + 16 + lr) * H2DIM + kb];
  }

  LBAR();                                 // bar3: h2s ready

  // ---- GEMM3: h2s[64,256] @ W3 -> + b3 -> out (f32, NT stores) ----
  {
    f32x4 acc[4][2] = {};
    #pragma unroll
    for (int kk = 0; kk < 4; ++kk){
      int kb = kk * 32 + lg * 8;
      #pragma unroll
      for (int m = 0; m < 4; ++m){
        int row = m * 16 + lr;
        bf16x8 a = *(const bf16x8*)&h2s[(row * H2DIM + kb) ^ ((row & 7) << 3)];
        acc[m][0] = __builtin_amdgcn_mfma_f32_16x16x32_bf16(a, b3b[kk*2  ], acc[m][0], 0, 0, 0);
        acc[m][1] = __builtin_amdgcn_mfma_f32_16x16x32_bf16(a, b3b[kk*2+1], acc[m][1], 0, 0, 0);
      }
    }
    // second B-batch (kk=4..7); latency hides under batch-1 MFMAs above
    #pragma unroll
    for (int kk = 0; kk < 4; ++kk){
      int kb = (kk + 4) * 32 + lg * 8;
      b3b[kk * 2    ] = *(const bf16x8*)&w3t[(col0      + lr) * H2DIM + kb];
      b3b[kk * 2 + 1] = *(const bf16x8*)&w3t[(col0 + 16 + lr) * H2DIM + kb];
    }
    #pragma unroll
    for (int kk = 0; kk < 4; ++kk){
      int kb = (kk + 4) * 32 + lg * 8;
      #pragma unroll
      for (int m = 0; m < 4; ++m){
        int row = m * 16 + lr;
        bf16x8 a = *(const bf16x8*)&h2s[(row * H2DIM + kb) ^ ((row & 7) << 3)];
        acc[m][0] = __builtin_amdgcn_mfma_f32_16x16x32_bf16(a, b3b[kk*2  ], acc[m][0], 0, 0, 0);
        acc[m][1] = __builtin_amdgcn_mfma_f32_16x16x32_bf16(a, b3b[kk*2+1], acc[m][1], 0, 0, 0);
      }
    }
    float* ob = out + (((size_t)strm * NBATCH + n) * LPTS + l0) * CDIM;
    #pragma unroll
    for (int nt = 0; nt < 2; ++nt){
      int col = col0 + nt * 16 + lr;
      float bias = b3[col];
      #pragma unroll
      for (int m = 0; m < 4; ++m){
        #pragma unroll
        for (int r = 0; r < 4; ++r){
          int row = m * 16 + lg * 4 + r;
          __builtin_nontemporal_store(acc[m][nt][r] + bias,
                                      &ob[(size_t)row * CDIM + col]);
        }
      }
    }
  }
}

extern "C" void kernel_launch(void* const* d_in, const int* in_sizes, int n_in,
                              void* d_out, int out_size, void* d_ws, size_t ws_size,
                              hipStream_t stream){
  const float* feat0 = (const float*)d_in[0];
  const float* feat1 = (const float*)d_in[1];
  const float* pts0  = (const float*)d_in[2];
  const float* pts1  = (const float*)d_in[3];
  const int*   anci  = (const int*)d_in[4];
  const int*   ancj  = (const int*)d_in[5];
  const float* W1    = (const float*)d_in[6];
  const float* b1    = (const float*)d_in[7];
  const float* W2    = (const float*)d_in[8];
  const float* b2    = (const float*)d_in[9];
  const float* W3    = (const float*)d_in[10];
  const float* b3    = (const float*)d_in[11];
  unsigned short* wt = (unsigned short*)d_ws;
  float* coef = (float*)((char*)d_ws + 327680);
  float* out = (float*)d_out;

  prep_weights<<<640, 256, 0, stream>>>(W1, W2, W3, wt);
  prep_coef<<<16, 128, 0, stream>>>(pts0, pts1, anci, ancj, W1, coef);
  fused<<<4096, 512, 0, stream>>>(feat0, feat1, pts0, pts1, anci, ancj,
                                  b1, b2, b3, wt, coef, out);
}